// Round 6
// baseline (625.456 us; speedup 1.0000x reference)
//
#include <hip/hip_runtime.h>

#define DEV static __device__ __forceinline__

typedef short bf16x8 __attribute__((ext_vector_type(8)));
typedef float floatx4 __attribute__((ext_vector_type(4)));
typedef unsigned short ushort4v __attribute__((ext_vector_type(4)));
typedef unsigned short ushort8v __attribute__((ext_vector_type(8)));

DEV unsigned short f32_bf16(float f) {
  unsigned int u = __builtin_bit_cast(unsigned int, f);
  u = u + 0x7fffu + ((u >> 16) & 1u);
  return (unsigned short)(u >> 16);
}
DEV float bf2f(unsigned short u) {
  unsigned int v = ((unsigned int)u) << 16;
  return __builtin_bit_cast(float, v);
}
DEV float sigmoidf_(float x) { return 1.0f / (1.0f + __expf(-x)); }
DEV float siluf_(float x) { return x * sigmoidf_(x); }

#define GLD_LDS16(g, l)                                                              \
  __builtin_amdgcn_global_load_lds((const __attribute__((address_space(1))) void*)(g), \
                                   (__attribute__((address_space(3))) void*)(l), 16, 0, 0)

// ---------------------------------------------------------------------------
// MFMA GEMM: C[M,N] = A[M,K] @ B[N,K]^T, bf16 in, 128x128 block tile, BK=64
// (two 32-k sub-tiles per barrier pair -> 32 MFMAs per vmcnt drain), LDS
// staging via global_load_lds(16B), XOR-swizzled k-chunks, GM=4 supertile
// swizzle. Split-K via blockIdx.z (bsA=bsB=Ksub, bsC=partial stride).
// MODE 0: fp32 store. MODE 1: bf16 store, optional dual-output split at
// col nsplit (second buffer Cv2 with ldc2; no batch offset on split path).
// ---------------------------------------------------------------------------
template <int MODE>
__global__ __launch_bounds__(256) void gemm128(
    const unsigned short* __restrict__ A, const unsigned short* __restrict__ B,
    void* __restrict__ Cv, int K, int lda, int ldb, int ldc,
    long long bsA, long long bsB, long long bsC,
    int nsplit, unsigned short* __restrict__ Cv2, int ldc2) {
  __shared__ unsigned short As[8192];
  __shared__ unsigned short Bs[8192];
  A += (long long)blockIdx.z * bsA;
  B += (long long)blockIdx.z * bsB;
  const long long coff = (long long)blockIdx.z * bsC;
  const int tid = threadIdx.x;
  const int w = tid >> 6, lane = tid & 63;

  const int nbx = gridDim.x, nby = gridDim.y;
  const int GM = 4;
  int bid = blockIdx.y * nbx + blockIdx.x;
  int gid = bid / (GM * nbx);
  int rem = bid - gid * (GM * nbx);
  int gsz = min(GM, nby - gid * GM);
  int mtile = gid * GM + rem % gsz;
  int ntile = rem / gsz;
  const int m0 = mtile << 7, n0 = ntile << 7;

  const int srow = lane >> 2;
  const int schunk = ((lane & 3) ^ (srow & 3)) * 8;
  const unsigned short* ag0 = A + (long long)(m0 + w * 32 + srow) * lda + schunk;
  const unsigned short* ag1 = ag0 + (long long)16 * lda;
  const unsigned short* bg0 = B + (long long)(n0 + w * 32 + srow) * ldb + schunk;
  const unsigned short* bg1 = bg0 + (long long)16 * ldb;
  unsigned short* al0 = As + (w * 32) * 32 + lane * 8;
  unsigned short* al1 = As + (w * 32 + 16) * 32 + lane * 8;
  unsigned short* bl0 = Bs + (w * 32) * 32 + lane * 8;
  unsigned short* bl1 = Bs + (w * 32 + 16) * 32 + lane * 8;

  const int wr = (w >> 1) << 6, wc = (w & 1) << 6;
  const int fr = lane & 15;
  const int slot = (((lane >> 4) ^ (fr & 3))) << 3;

  floatx4 acc[4][4];
#pragma unroll
  for (int i = 0; i < 4; ++i)
#pragma unroll
    for (int j = 0; j < 4; ++j) acc[i][j] = (floatx4){0.f, 0.f, 0.f, 0.f};

  for (int k0 = 0; k0 < K; k0 += 64) {
    __syncthreads();
    GLD_LDS16(ag0 + k0, al0);
    GLD_LDS16(ag1 + k0, al1);
    GLD_LDS16(ag0 + k0 + 32, al0 + 4096);
    GLD_LDS16(ag1 + k0 + 32, al1 + 4096);
    GLD_LDS16(bg0 + k0, bl0);
    GLD_LDS16(bg1 + k0, bl1);
    GLD_LDS16(bg0 + k0 + 32, bl0 + 4096);
    GLD_LDS16(bg1 + k0 + 32, bl1 + 4096);
    __syncthreads();
#pragma unroll
    for (int s = 0; s < 2; ++s) {
      const unsigned short* Ab = As + s * 4096;
      const unsigned short* Bb = Bs + s * 4096;
      bf16x8 af[4], bf_[4];
#pragma unroll
      for (int i = 0; i < 4; ++i) af[i] = *(const bf16x8*)(Ab + (wr + i * 16 + fr) * 32 + slot);
#pragma unroll
      for (int j = 0; j < 4; ++j) bf_[j] = *(const bf16x8*)(Bb + (wc + j * 16 + fr) * 32 + slot);
#pragma unroll
      for (int i = 0; i < 4; ++i)
#pragma unroll
        for (int j = 0; j < 4; ++j)
          acc[i][j] = __builtin_amdgcn_mfma_f32_16x16x32_bf16(af[i], bf_[j], acc[i][j], 0, 0, 0);
    }
  }

  const int r0 = (lane >> 4) << 2;
#pragma unroll
  for (int i = 0; i < 4; ++i) {
#pragma unroll
    for (int j = 0; j < 4; ++j) {
      int col = n0 + wc + j * 16 + fr;
      int row = m0 + wr + i * 16 + r0;
#pragma unroll
      for (int r = 0; r < 4; ++r) {
        float v = acc[i][j][r];
        if constexpr (MODE == 0) {
          ((float*)Cv)[coff + (long long)(row + r) * ldc + col] = v;
        } else {
          if (col < nsplit)
            ((unsigned short*)Cv)[coff + (long long)(row + r) * ldc + col] = f32_bf16(v);
          else
            Cv2[(long long)(row + r) * ldc2 + (col - nsplit)] = f32_bf16(v);
        }
      }
    }
  }
}

// ---------------------------------------------------------------------------
// Fused gate+up+swiglu: act = bf16(silu(A@Bg^T) * (A@Bu^T)). Same structure,
// triple staging (A, Bg, Bu), dual accumulators. LDS 48 KB.
// ---------------------------------------------------------------------------
__global__ __launch_bounds__(256) void gemm128_glu(
    const unsigned short* __restrict__ A, const unsigned short* __restrict__ Bg,
    const unsigned short* __restrict__ Bu, unsigned short* __restrict__ act,
    int K, int lda, int ldb, int ldc) {
  __shared__ unsigned short As[8192];
  __shared__ unsigned short Bgs[8192];
  __shared__ unsigned short Bus[8192];
  const int tid = threadIdx.x;
  const int w = tid >> 6, lane = tid & 63;

  const int nbx = gridDim.x, nby = gridDim.y;
  const int GM = 4;
  int bid = blockIdx.y * nbx + blockIdx.x;
  int gid = bid / (GM * nbx);
  int rem = bid - gid * (GM * nbx);
  int gsz = min(GM, nby - gid * GM);
  int mtile = gid * GM + rem % gsz;
  int ntile = rem / gsz;
  const int m0 = mtile << 7, n0 = ntile << 7;

  const int srow = lane >> 2;
  const int schunk = ((lane & 3) ^ (srow & 3)) * 8;
  const unsigned short* ag0 = A + (long long)(m0 + w * 32 + srow) * lda + schunk;
  const unsigned short* ag1 = ag0 + (long long)16 * lda;
  const unsigned short* gg0 = Bg + (long long)(n0 + w * 32 + srow) * ldb + schunk;
  const unsigned short* gg1 = gg0 + (long long)16 * ldb;
  const unsigned short* ug0 = Bu + (long long)(n0 + w * 32 + srow) * ldb + schunk;
  const unsigned short* ug1 = ug0 + (long long)16 * ldb;
  unsigned short* al0 = As + (w * 32) * 32 + lane * 8;
  unsigned short* al1 = As + (w * 32 + 16) * 32 + lane * 8;
  unsigned short* gl0 = Bgs + (w * 32) * 32 + lane * 8;
  unsigned short* gl1 = Bgs + (w * 32 + 16) * 32 + lane * 8;
  unsigned short* ul0 = Bus + (w * 32) * 32 + lane * 8;
  unsigned short* ul1 = Bus + (w * 32 + 16) * 32 + lane * 8;

  const int wr = (w >> 1) << 6, wc = (w & 1) << 6;
  const int fr = lane & 15;
  const int slot = (((lane >> 4) ^ (fr & 3))) << 3;

  floatx4 accg[4][4], accu[4][4];
#pragma unroll
  for (int i = 0; i < 4; ++i)
#pragma unroll
    for (int j = 0; j < 4; ++j) {
      accg[i][j] = (floatx4){0.f, 0.f, 0.f, 0.f};
      accu[i][j] = (floatx4){0.f, 0.f, 0.f, 0.f};
    }

  for (int k0 = 0; k0 < K; k0 += 64) {
    __syncthreads();
    GLD_LDS16(ag0 + k0, al0);
    GLD_LDS16(ag1 + k0, al1);
    GLD_LDS16(ag0 + k0 + 32, al0 + 4096);
    GLD_LDS16(ag1 + k0 + 32, al1 + 4096);
    GLD_LDS16(gg0 + k0, gl0);
    GLD_LDS16(gg1 + k0, gl1);
    GLD_LDS16(gg0 + k0 + 32, gl0 + 4096);
    GLD_LDS16(gg1 + k0 + 32, gl1 + 4096);
    GLD_LDS16(ug0 + k0, ul0);
    GLD_LDS16(ug1 + k0, ul1);
    GLD_LDS16(ug0 + k0 + 32, ul0 + 4096);
    GLD_LDS16(ug1 + k0 + 32, ul1 + 4096);
    __syncthreads();
#pragma unroll
    for (int s = 0; s < 2; ++s) {
      const unsigned short* Ab = As + s * 4096;
      const unsigned short* Gb = Bgs + s * 4096;
      const unsigned short* Ub = Bus + s * 4096;
      bf16x8 af[4], bf_[4];
#pragma unroll
      for (int i = 0; i < 4; ++i) af[i] = *(const bf16x8*)(Ab + (wr + i * 16 + fr) * 32 + slot);
#pragma unroll
      for (int j = 0; j < 4; ++j) bf_[j] = *(const bf16x8*)(Gb + (wc + j * 16 + fr) * 32 + slot);
#pragma unroll
      for (int i = 0; i < 4; ++i)
#pragma unroll
        for (int j = 0; j < 4; ++j)
          accg[i][j] = __builtin_amdgcn_mfma_f32_16x16x32_bf16(af[i], bf_[j], accg[i][j], 0, 0, 0);
#pragma unroll
      for (int j = 0; j < 4; ++j) bf_[j] = *(const bf16x8*)(Ub + (wc + j * 16 + fr) * 32 + slot);
#pragma unroll
      for (int i = 0; i < 4; ++i)
#pragma unroll
        for (int j = 0; j < 4; ++j)
          accu[i][j] = __builtin_amdgcn_mfma_f32_16x16x32_bf16(af[i], bf_[j], accu[i][j], 0, 0, 0);
    }
  }

  const int r0 = (lane >> 4) << 2;
#pragma unroll
  for (int i = 0; i < 4; ++i) {
#pragma unroll
    for (int j = 0; j < 4; ++j) {
      long long base = (long long)(m0 + wr + i * 16 + r0) * ldc + (n0 + wc + j * 16 + fr);
#pragma unroll
      for (int r = 0; r < 4; ++r)
        act[base + (long long)r * ldc] = f32_bf16(siluf_(accg[i][j][r]) * accu[i][j][r]);
    }
  }
}

// ---------------------------------------------------------------------------
// small GEMM (direct-from-global), used only for the N=32 dt projection.
// ---------------------------------------------------------------------------
template <int WM>
__global__ __launch_bounds__(256) void gemm_small_nt(
    const unsigned short* __restrict__ A, const unsigned short* __restrict__ B,
    float* __restrict__ C, int M, int N, int K, int lda, int ldb, int ldc) {
  const int w = threadIdx.x >> 6;
  const int lane = threadIdx.x & 63;
  const int lm = lane & 15;
  const int ko = (lane >> 4) << 3;
  const int bn0 = blockIdx.x << 6;
  const int m_base = blockIdx.y * (WM * 64) + w * (WM * 16);

  const unsigned short* arow[WM];
#pragma unroll
  for (int i = 0; i < WM; ++i) arow[i] = A + (long long)(m_base + i * 16 + lm) * lda + ko;
  int nv = (N - bn0) >> 4;
  nv = nv > 4 ? 4 : nv;
  const unsigned short* brow[4];
#pragma unroll
  for (int j = 0; j < 4; ++j) {
    int nr = bn0 + j * 16 + lm;
    brow[j] = B + (long long)(j < nv ? nr : 0) * ldb + ko;
  }
  floatx4 acc[WM][4];
#pragma unroll
  for (int i = 0; i < WM; ++i)
#pragma unroll
    for (int j = 0; j < 4; ++j) acc[i][j] = (floatx4){0.f, 0.f, 0.f, 0.f};
  for (int k0 = 0; k0 < K; k0 += 32) {
    bf16x8 a[WM];
#pragma unroll
    for (int i = 0; i < WM; ++i) a[i] = *(const bf16x8*)(arow[i] + k0);
#pragma unroll
    for (int j = 0; j < 4; ++j) {
      if (j < nv) {
        bf16x8 b = *(const bf16x8*)(brow[j] + k0);
#pragma unroll
        for (int i = 0; i < WM; ++i)
          acc[i][j] = __builtin_amdgcn_mfma_f32_16x16x32_bf16(a[i], b, acc[i][j], 0, 0, 0);
      }
    }
  }
  const int r0 = (lane >> 4) << 2;
#pragma unroll
  for (int i = 0; i < WM; ++i)
#pragma unroll
    for (int j = 0; j < 4; ++j)
      if (j < nv) {
        int col = bn0 + j * 16 + lm;
        long long base = (long long)(m_base + i * 16 + r0) * ldc + col;
#pragma unroll
        for (int r = 0; r < 4; ++r) C[base + (long long)r * ldc] = acc[i][j][r];
      }
}

// ---------------------------------------------------------------------------
__global__ __launch_bounds__(256) void f32_to_bf16_k(const float* __restrict__ src,
                                                     unsigned short* __restrict__ dst,
                                                     long long n4) {
  long long i = (long long)blockIdx.x * 256 + threadIdx.x;
  if (i < n4) {
    float4 v = ((const float4*)src)[i];
    ushort4v o = {f32_bf16(v.x), f32_bf16(v.y), f32_bf16(v.z), f32_bf16(v.w)};
    ((ushort4v*)dst)[i] = o;
  }
}

__global__ __launch_bounds__(256) void zero_out_k(float* __restrict__ o, long long n) {
  long long i = (long long)blockIdx.x * 256 + threadIdx.x;
  if (i < n) o[i] = 0.f;
}

// ---------------------------------------------------------------------------
__global__ __launch_bounds__(256) void rmsnorm1024_bf16_k(const float* __restrict__ x,
                                                          const float* __restrict__ w,
                                                          unsigned short* __restrict__ out,
                                                          float eps) {
  long long row = blockIdx.x;
  int t = threadIdx.x;
  float4 v = ((const float4*)(x + row * 1024))[t];
  float ss = v.x * v.x + v.y * v.y + v.z * v.z + v.w * v.w;
  __shared__ float red[4];
#pragma unroll
  for (int o = 32; o > 0; o >>= 1) ss += __shfl_down(ss, o, 64);
  if ((t & 63) == 0) red[t >> 6] = ss;
  __syncthreads();
  float tot = red[0] + red[1] + red[2] + red[3];
  float sc = rsqrtf(tot * (1.0f / 1024.0f) + eps);
  float4 wv = ((const float4*)w)[t];
  ushort4v o = {f32_bf16(v.x * sc * wv.x), f32_bf16(v.y * sc * wv.y),
                f32_bf16(v.z * sc * wv.z), f32_bf16(v.w * sc * wv.w)};
  ((ushort4v*)(out + row * 1024))[t] = o;
}

// ---------------------------------------------------------------------------
__global__ __launch_bounds__(256) void add_rmsnorm_k(const float* __restrict__ hs,
                                                     const float* __restrict__ parts,
                                                     long long pstride, int np,
                                                     const float* __restrict__ w,
                                                     float* __restrict__ mh,
                                                     unsigned short* __restrict__ h2, float eps) {
  long long row = blockIdx.x;
  int t = threadIdx.x;
  float4 v = ((const float4*)(hs + row * 1024))[t];
  for (int p = 0; p < np; ++p) {
    float4 u = ((const float4*)(parts + p * pstride + row * 1024))[t];
    v.x += u.x;
    v.y += u.y;
    v.z += u.z;
    v.w += u.w;
  }
  ((float4*)(mh + row * 1024))[t] = v;
  float ss = v.x * v.x + v.y * v.y + v.z * v.z + v.w * v.w;
  __shared__ float red[4];
#pragma unroll
  for (int o = 32; o > 0; o >>= 1) ss += __shfl_down(ss, o, 64);
  if ((t & 63) == 0) red[t >> 6] = ss;
  __syncthreads();
  float tot = red[0] + red[1] + red[2] + red[3];
  float sc = rsqrtf(tot * (1.0f / 1024.0f) + eps);
  float4 wv = ((const float4*)w)[t];
  ushort4v o = {f32_bf16(v.x * sc * wv.x), f32_bf16(v.y * sc * wv.y),
                f32_bf16(v.z * sc * wv.z), f32_bf16(v.w * sc * wv.w)};
  ((ushort4v*)(h2 + row * 1024))[t] = o;
}

// ---------------------------------------------------------------------------
__global__ __launch_bounds__(256) void addn_f32_k(const float* __restrict__ a,
                                                  const float* __restrict__ parts,
                                                  long long pstride, int np,
                                                  float* __restrict__ o, long long n4) {
  long long i = (long long)blockIdx.x * 256 + threadIdx.x;
  if (i < n4) {
    float4 x = ((const float4*)a)[i];
    for (int p = 0; p < np; ++p) {
      float4 u = ((const float4*)(parts + p * pstride))[i];
      x.x += u.x;
      x.y += u.y;
      x.z += u.z;
      x.w += u.w;
    }
    ((float4*)o)[i] = x;
  }
}

// ---------------------------------------------------------------------------
__global__ __launch_bounds__(256) void gated_rmsnorm2048_k(const unsigned short* __restrict__ y,
                                                           const unsigned short* __restrict__ z,
                                                           const float* __restrict__ w,
                                                           unsigned short* __restrict__ out,
                                                           float eps) {
  long long row = blockIdx.x;
  int t = threadIdx.x;
  ushort8v yv = ((const ushort8v*)(y + row * 2048))[t];
  ushort8v zv = ((const ushort8v*)(z + row * 2048))[t];
  float g[8];
  float ss = 0.f;
#pragma unroll
  for (int j = 0; j < 8; ++j) {
    g[j] = bf2f(yv[j]) * siluf_(bf2f(zv[j]));
    ss += g[j] * g[j];
  }
  __shared__ float red[4];
#pragma unroll
  for (int o = 32; o > 0; o >>= 1) ss += __shfl_down(ss, o, 64);
  if ((t & 63) == 0) red[t >> 6] = ss;
  __syncthreads();
  float tot = red[0] + red[1] + red[2] + red[3];
  float sc = rsqrtf(tot * (1.0f / 2048.0f) + eps);
  float ww[8];
  *(float4*)&ww[0] = ((const float4*)w)[2 * t];
  *(float4*)&ww[4] = ((const float4*)w)[2 * t + 1];
  ushort8v o;
#pragma unroll
  for (int j = 0; j < 8; ++j) o[j] = f32_bf16(g[j] * sc * ww[j]);
  ((ushort8v*)(out + row * 2048))[t] = o;
}

// ---------------------------------------------------------------------------
__global__ __launch_bounds__(256) void conv_silu_k(const unsigned short* __restrict__ xraw,
                                                   const float* __restrict__ wconv,
                                                   const float* __restrict__ bconv,
                                                   unsigned short* __restrict__ xBC) {
  int m = blockIdx.x;
  int l = m & 2047;
  for (int ch = threadIdx.x; ch < 2304; ch += 256) {
    float acc = bconv[ch];
#pragma unroll
    for (int k = 0; k < 4; ++k) {
      int lk = l + k - 3;
      if (lk >= 0) acc += bf2f(xraw[(long long)(m + k - 3) * 2304 + ch]) * wconv[ch * 4 + k];
    }
    xBC[(long long)m * 2304 + ch] = f32_bf16(siluf_(acc));
  }
}

// ---------------------------------------------------------------------------
__global__ __launch_bounds__(256) void dt_softplus_k(const float* __restrict__ dtraw,
                                                     const float* __restrict__ dt_bias,
                                                     float* __restrict__ dt_s) {
  int i = blockIdx.x * 256 + threadIdx.x;
  float xv = dtraw[i] + dt_bias[i & 31];
  dt_s[i] = xv > 20.f ? xv : log1pf(expf(xv));
}

// ---------------------------------------------------------------------------
__global__ __launch_bounds__(128) void dA_cumsum_k(const float* __restrict__ dt_s,
                                                   const float* __restrict__ A_log,
                                                   float* __restrict__ dA_cs) {
  int bi = blockIdx.x;
  int c = bi & 15, h = (bi >> 4) & 31, b = bi >> 9;
  int q = threadIdx.x;
  float A = -expf(A_log[h]);
  float v = dt_s[((long long)(b * 2048 + c * 128 + q)) * 32 + h] * A;
  __shared__ float sbuf[128];
  sbuf[q] = v;
  __syncthreads();
  for (int off = 1; off < 128; off <<= 1) {
    float tv = (q >= off) ? sbuf[q - off] : 0.f;
    __syncthreads();
    sbuf[q] += tv;
    __syncthreads();
  }
  dA_cs[(long long)bi * 128 + q] = sbuf[q];
}

// ---------------------------------------------------------------------------
// S3 (MFMA): Y_diag -> y bf16, local states -> states bf16.
// ---------------------------------------------------------------------------
__global__ __launch_bounds__(256) void ssd_diag_states_k(
    const unsigned short* __restrict__ xBC, const float* __restrict__ dt_s,
    const float* __restrict__ dA_cs, const unsigned short* __restrict__ G,
    unsigned short* __restrict__ y, unsigned short* __restrict__ states) {
  __shared__ unsigned short Mz[128 * 136];
  __shared__ unsigned short xdT[64 * 136];
  __shared__ float Acs[128];
  __shared__ float wdec[128];
  const int bx = blockIdx.x;
  const int h = bx & 31, c = (bx >> 5) & 15, b = bx >> 9;
  const int t = threadIdx.x;
  const int w = t >> 6, lane = t & 63, fr = lane & 15, hi = lane >> 4;
  const long long rowbase = (long long)b * 2048 + c * 128;
  const long long abase = ((long long)((b * 32 + h) * 16 + c)) << 7;

  if (t < 128) {
    float a = dA_cs[abase + t];
    Acs[t] = a;
    wdec[t] = __expf(dA_cs[abase + 127] - a);
  }
  {
    int s = t >> 1, p0 = (t & 1) * 32;
    float dtv = dt_s[(rowbase + s) * 32 + h];
    const ushort8v* xv = (const ushort8v*)(xBC + (rowbase + s) * 2304 + h * 64 + p0);
#pragma unroll
    for (int i = 0; i < 4; ++i) {
      ushort8v vv = xv[i];
#pragma unroll
      for (int j = 0; j < 8; ++j) xdT[(p0 + i * 8 + j) * 136 + s] = f32_bf16(bf2f(vv[j]) * dtv);
    }
  }
  __syncthreads();
  {
    int q = t >> 1, s0 = (t & 1) * 64;
    float aq = Acs[q];
    const ushort8v* gv =
        (const ushort8v*)(G + (((long long)(b * 16 + c)) * 128 + q) * 128 + s0);
#pragma unroll
    for (int i = 0; i < 8; ++i) {
      ushort8v gg = gv[i];
#pragma unroll
      for (int j = 0; j < 8; ++j) {
        int s = s0 + i * 8 + j;
        float m = (s <= q) ? bf2f(gg[j]) * __expf(aq - Acs[s]) : 0.f;
        Mz[q * 136 + s] = f32_bf16(m);
      }
    }
  }
  __syncthreads();
  const int q0 = w << 5;
  {
    floatx4 acc[2][4];
#pragma unroll
    for (int i = 0; i < 2; ++i)
#pragma unroll
      for (int j = 0; j < 4; ++j) acc[i][j] = (floatx4){0.f, 0.f, 0.f, 0.f};
#pragma unroll
    for (int k0 = 0; k0 < 128; k0 += 32) {
      int kk = k0 + hi * 8;
      bf16x8 a0 = *(const bf16x8*)(Mz + (q0 + fr) * 136 + kk);
      bf16x8 a1 = *(const bf16x8*)(Mz + (q0 + 16 + fr) * 136 + kk);
      bf16x8 bf_[4];
#pragma unroll
      for (int j = 0; j < 4; ++j) bf_[j] = *(const bf16x8*)(xdT + (j * 16 + fr) * 136 + kk);
#pragma unroll
      for (int j = 0; j < 4; ++j) {
        acc[0][j] = __builtin_amdgcn_mfma_f32_16x16x32_bf16(a0, bf_[j], acc[0][j], 0, 0, 0);
        acc[1][j] = __builtin_amdgcn_mfma_f32_16x16x32_bf16(a1, bf_[j], acc[1][j], 0, 0, 0);
      }
    }
#pragma unroll
    for (int i = 0; i < 2; ++i)
#pragma unroll
      for (int r = 0; r < 4; ++r) {
        int q = q0 + i * 16 + hi * 4 + r;
        unsigned short* yrow = y + (rowbase + q) * 2048 + h * 64;
#pragma unroll
        for (int j = 0; j < 4; ++j) yrow[j * 16 + fr] = f32_bf16(acc[i][j][r]);
      }
  }
  __syncthreads();
  {
    int s = t >> 1, n0 = (t & 1) * 64;
    float wd = wdec[s];
    const ushort8v* bv = (const ushort8v*)(xBC + (rowbase + s) * 2304 + 2048 + n0);
#pragma unroll
    for (int i = 0; i < 8; ++i) {
      ushort8v bb = bv[i];
#pragma unroll
      for (int j = 0; j < 8; ++j) Mz[(n0 + i * 8 + j) * 136 + s] = f32_bf16(bf2f(bb[j]) * wd);
    }
  }
  __syncthreads();
  {
    floatx4 acc[2][4];
#pragma unroll
    for (int i = 0; i < 2; ++i)
#pragma unroll
      for (int j = 0; j < 4; ++j) acc[i][j] = (floatx4){0.f, 0.f, 0.f, 0.f};
#pragma unroll
    for (int k0 = 0; k0 < 128; k0 += 32) {
      int kk = k0 + hi * 8;
      bf16x8 a0 = *(const bf16x8*)(Mz + (q0 + fr) * 136 + kk);
      bf16x8 a1 = *(const bf16x8*)(Mz + (q0 + 16 + fr) * 136 + kk);
      bf16x8 bf_[4];
#pragma unroll
      for (int j = 0; j < 4; ++j) bf_[j] = *(const bf16x8*)(xdT + (j * 16 + fr) * 136 + kk);
#pragma unroll
      for (int j = 0; j < 4; ++j) {
        acc[0][j] = __builtin_amdgcn_mfma_f32_16x16x32_bf16(a0, bf_[j], acc[0][j], 0, 0, 0);
        acc[1][j] = __builtin_amdgcn_mfma_f32_16x16x32_bf16(a1, bf_[j], acc[1][j], 0, 0, 0);
      }
    }
    unsigned short* st = states + (long long)bx * 8192;
#pragma unroll
    for (int i = 0; i < 2; ++i)
#pragma unroll
      for (int j = 0; j < 4; ++j) {
        int p = j * 16 + fr;
        int n = q0 + i * 16 + hi * 4;
        ushort4v o;
#pragma unroll
        for (int r = 0; r < 4; ++r) o[r] = f32_bf16(acc[i][j][r]);
        *(ushort4v*)(st + p * 128 + n) = o;
      }
  }
}

// ---------------------------------------------------------------------------
__global__ __launch_bounds__(256) void ssd_scan_k(const float* __restrict__ dA_cs,
                                                  unsigned short* __restrict__ states) {
  int h = blockIdx.x & 31, b = blockIdx.x >> 5;
  int t = threadIdx.x;
  float carry[32];
#pragma unroll
  for (int i = 0; i < 32; ++i) carry[i] = 0.f;
  for (int c = 0; c < 16; ++c) {
    long long base = ((long long)((b * 16 + c) * 32 + h)) * 8192;
    float dec = __expf(dA_cs[(((long long)((b * 32 + h) * 16 + c)) << 7) + 127]);
#pragma unroll
    for (int i = 0; i < 32; ++i) {
      long long idx = base + t + i * 256;
      float local = bf2f(states[idx]);
      states[idx] = f32_bf16(carry[i]);
      carry[i] = dec * carry[i] + local;
    }
  }
}

// ---------------------------------------------------------------------------
__global__ __launch_bounds__(256) void ssd_off_k(const unsigned short* __restrict__ xBC,
                                                 const float* __restrict__ dA_cs,
                                                 const unsigned short* __restrict__ states,
                                                 const float* __restrict__ Dvec,
                                                 unsigned short* __restrict__ y) {
  __shared__ float eA[128];
  const int bx = blockIdx.x;
  const int h = bx & 31, c = (bx >> 5) & 15, b = bx >> 9;
  const int t = threadIdx.x;
  const int w = t >> 6, lane = t & 63, fr = lane & 15, hi = lane >> 4;
  const long long rowbase = (long long)b * 2048 + c * 128;
  const long long abase = ((long long)((b * 32 + h) * 16 + c)) << 7;
  if (t < 128) eA[t] = __expf(dA_cs[abase + t]);
  __syncthreads();

  const unsigned short* st = states + (long long)bx * 8192;
  const int q0 = w << 5;
  floatx4 acc[2][4];
#pragma unroll
  for (int i = 0; i < 2; ++i)
#pragma unroll
    for (int j = 0; j < 4; ++j) acc[i][j] = (floatx4){0.f, 0.f, 0.f, 0.f};

#pragma unroll
  for (int k0 = 0; k0 < 128; k0 += 32) {
    int kk = k0 + hi * 8;
    bf16x8 a0 = *(const bf16x8*)(xBC + (rowbase + q0 + fr) * 2304 + 2176 + kk);
    bf16x8 a1 = *(const bf16x8*)(xBC + (rowbase + q0 + 16 + fr) * 2304 + 2176 + kk);
    bf16x8 bf_[4];
#pragma unroll
    for (int j = 0; j < 4; ++j) bf_[j] = *(const bf16x8*)(st + (j * 16 + fr) * 128 + kk);
#pragma unroll
    for (int j = 0; j < 4; ++j) {
      acc[0][j] = __builtin_amdgcn_mfma_f32_16x16x32_bf16(a0, bf_[j], acc[0][j], 0, 0, 0);
      acc[1][j] = __builtin_amdgcn_mfma_f32_16x16x32_bf16(a1, bf_[j], acc[1][j], 0, 0, 0);
    }
  }

  float Dh = Dvec[h];
#pragma unroll
  for (int i = 0; i < 2; ++i) {
#pragma unroll
    for (int r = 0; r < 4; ++r) {
      int q = q0 + i * 16 + hi * 4 + r;
      float e = eA[q];
      const unsigned short* xrow = xBC + (rowbase + q) * 2304 + h * 64;
      unsigned short* yrow = y + (rowbase + q) * 2048 + h * 64;
#pragma unroll
      for (int j = 0; j < 4; ++j) {
        int p = j * 16 + fr;
        float v = bf2f(yrow[p]) + e * acc[i][j][r] + Dh * bf2f(xrow[p]);
        yrow[p] = f32_bf16(v);
      }
    }
  }
}

// ---------------------------------------------------------------------------
extern "C" void kernel_launch(void* const* d_in, const int* in_sizes, int n_in, void* d_out,
                              int out_size, void* d_ws, size_t ws_size, hipStream_t stream) {
  const float* hs = (const float*)d_in[0];
  const float* w_ln1 = (const float*)d_in[1];
  const float* w_in = (const float*)d_in[2];
  const float* w_conv = (const float*)d_in[3];
  const float* b_conv = (const float*)d_in[4];
  const float* dt_bias = (const float*)d_in[5];
  const float* A_log = (const float*)d_in[6];
  const float* Dvec = (const float*)d_in[7];
  const float* w_mnorm = (const float*)d_in[8];
  const float* w_out = (const float*)d_in[9];
  const float* w_ln2 = (const float*)d_in[10];
  const float* w_gate = (const float*)d_in[11];
  const float* w_up = (const float*)d_in[12];
  const float* w_down = (const float*)d_in[13];
  float* out = (float*)d_out;
  const int M = 4096;
  const int NOSPLIT = 1 << 30;

  char* ws = (char*)d_ws;
  const size_t R0 = 0;               // z bf16 -> oproj partials (w/ R1) -> act bf16
  const size_t R1 = 33554432;        // xraw bf16 -> states+y bf16 -> partials -> down partials
  const size_t R1b = R1 + 33554432;  // wbf_out
  const size_t R2 = 71303168;        // xBC bf16 -> ygn -> h2
  const size_t R3 = 90177536;        // hnorm+wbf_in -> dt_s/dA/G -> mh
  const size_t R4 = 107544576;       // dtraw fp32
  const size_t W0 = 108068864;       // wbf_gate | wbf_up | wbf_down
  const size_t NEED = 133234688;

  if (ws_size < NEED) {
    hipLaunchKernelGGL(zero_out_k, dim3((out_size + 255) / 256), dim3(256), 0, stream, out,
                       (long long)out_size);
    return;
  }

  unsigned short* z = (unsigned short*)(ws + R0);
  unsigned short* act = (unsigned short*)(ws + R0);
  float* oproj_parts = (float*)(ws + R0);
  unsigned short* xraw = (unsigned short*)(ws + R1);
  unsigned short* states = (unsigned short*)(ws + R1);
  unsigned short* ybuf = (unsigned short*)(ws + R1 + 16777216);
  float* down_parts = (float*)(ws + R1);
  unsigned short* wbf_out = (unsigned short*)(ws + R1b);
  unsigned short* xBC = (unsigned short*)(ws + R2);
  unsigned short* ygn = (unsigned short*)(ws + R2);
  unsigned short* h2 = (unsigned short*)(ws + R2);
  unsigned short* hnorm = (unsigned short*)(ws + R3);
  unsigned short* wbf_in = (unsigned short*)(ws + R3 + 8388608);
  float* dt_s = (float*)(ws + R3);
  float* dA_cs = (float*)(ws + R3 + 524288);
  unsigned short* Gbuf = (unsigned short*)(ws + R3 + 1048576);
  float* mh = (float*)(ws + R3);
  float* dtraw = (float*)(ws + R4);
  unsigned short* wbf_gate = (unsigned short*)(ws + W0);
  unsigned short* wbf_up = (unsigned short*)(ws + W0 + 8388608);
  unsigned short* wbf_down = (unsigned short*)(ws + W0 + 16777216);

  // s1: rmsnorm(ln1) -> hnorm bf16
  hipLaunchKernelGGL(rmsnorm1024_bf16_k, dim3(M), dim3(256), 0, stream, hs, w_ln1, hnorm, 1e-6f);
  // s2: weight conversions
  hipLaunchKernelGGL(f32_to_bf16_k, dim3(4384), dim3(256), 0, stream, w_in, wbf_in, 1122304LL);
  hipLaunchKernelGGL(f32_to_bf16_k, dim3(4096), dim3(256), 0, stream, w_gate, wbf_gate, 1048576LL);
  hipLaunchKernelGGL(f32_to_bf16_k, dim3(4096), dim3(256), 0, stream, w_up, wbf_up, 1048576LL);
  hipLaunchKernelGGL(f32_to_bf16_k, dim3(4096), dim3(256), 0, stream, w_down, wbf_down, 1048576LL);
  // s3: in_proj merged (z cols 0..2047, xBC cols 2048..4351) + dt
  hipLaunchKernelGGL((gemm128<1>), dim3(34, 32, 1), dim3(256), 0, stream, hnorm, wbf_in, (void*)z,
                     1024, 1024, 1024, 2048, 0LL, 0LL, 0LL, 2048, xraw, 2304);
  hipLaunchKernelGGL((gemm_small_nt<4>), dim3(1, 16, 1), dim3(256), 0, stream, hnorm,
                     wbf_in + 4352 * 1024, dtraw, M, 32, 1024, 1024, 1024, 32);
  // s4: conv + silu -> xBC bf16
  hipLaunchKernelGGL(conv_silu_k, dim3(M), dim3(256), 0, stream, xraw, w_conv, b_conv, xBC);
  // s4b: w_out conversion
  hipLaunchKernelGGL(f32_to_bf16_k, dim3(2048), dim3(256), 0, stream, w_out, wbf_out, 524288LL);
  // s5: dt softplus
  hipLaunchKernelGGL(dt_softplus_k, dim3(512), dim3(256), 0, stream, dtraw, dt_bias, dt_s);
  // s6: dA cumsum
  hipLaunchKernelGGL(dA_cumsum_k, dim3(1024), dim3(128), 0, stream, dt_s, A_log, dA_cs);
  // s7: G = C @ B^T per chunk, stored bf16
  hipLaunchKernelGGL((gemm128<1>), dim3(1, 1, 32), dim3(256), 0, stream, xBC + 2176, xBC + 2048,
                     (void*)Gbuf, 128, 2304, 2304, 128, 294912LL, 294912LL, 16384LL, NOSPLIT,
                     (unsigned short*)nullptr, 0);
  // s8: Y_diag + local states (MFMA)
  hipLaunchKernelGGL(ssd_diag_states_k, dim3(1024), dim3(256), 0, stream, xBC, dt_s, dA_cs, Gbuf,
                     ybuf, states);
  // s9: inter-chunk scan
  hipLaunchKernelGGL(ssd_scan_k, dim3(64), dim3(256), 0, stream, dA_cs, states);
  // s10: Y_off + D-skip (MFMA)
  hipLaunchKernelGGL(ssd_off_k, dim3(1024), dim3(256), 0, stream, xBC, dA_cs, states, Dvec, ybuf);
  // s11: gated rmsnorm -> ygn bf16
  hipLaunchKernelGGL(gated_rmsnorm2048_k, dim3(M), dim3(256), 0, stream, ybuf, z, w_mnorm, ygn,
                     1e-5f);
  // s12: out_proj, split-K=4 -> 4 fp32 partials
  hipLaunchKernelGGL((gemm128<0>), dim3(8, 32, 4), dim3(256), 0, stream, ygn, wbf_out,
                     (void*)oproj_parts, 512, 2048, 2048, 1024, 512LL, 512LL, 4194304LL, NOSPLIT,
                     (unsigned short*)nullptr, 0);
  // s13: mh = hs + sum(partials); h2 = rmsnorm(mh, ln2)  [fused]
  hipLaunchKernelGGL(add_rmsnorm_k, dim3(M), dim3(256), 0, stream, hs, oproj_parts, 4194304LL, 4,
                     w_ln2, mh, h2, 1e-6f);
  // s15: fused gate+up+swiglu -> act bf16
  hipLaunchKernelGGL(gemm128_glu, dim3(32, 32, 1), dim3(256), 0, stream, h2, wbf_gate, wbf_up, act,
                     1024, 1024, 1024, 4096);
  // s17: down, split-K=2 -> 2 fp32 partials
  hipLaunchKernelGGL((gemm128<0>), dim3(8, 32, 2), dim3(256), 0, stream, act, wbf_down,
                     (void*)down_parts, 2048, 4096, 4096, 1024, 2048LL, 2048LL, 4194304LL, NOSPLIT,
                     (unsigned short*)nullptr, 0);
  // s18: out = mh + sum(partials)
  hipLaunchKernelGGL(addn_f32_k, dim3(4096), dim3(256), 0, stream, mh, down_parts, 4194304LL, 2,
                     out, 1048576LL);
}